// Round 7
// baseline (614.466 us; speedup 1.0000x reference)
//
#include <hip/hip_runtime.h>

#define B_ 4096
#define T_ 512
#define F_ 8
#define H_ 16

typedef float f32x2 __attribute__((ext_vector_type(2)));
typedef float f32x4v __attribute__((ext_vector_type(4)));

__device__ __forceinline__ f32x2 pkfma(f32x2 a, f32x2 b, f32x2 c) {
    return __builtin_elementwise_fma(a, b, c);
}
#define SV2(v, a, b) __builtin_shufflevector(v, v, a, b)

#define LOG2E 1.442695041f
#define N2LOG2E (-2.885390082f)

__device__ __forceinline__ float sigf(float x) {
    return __builtin_amdgcn_rcpf(1.0f + __builtin_amdgcn_exp2f(-LOG2E * x));
}
__device__ __forceinline__ float tanh_f(float x) {
    return __builtin_fmaf(2.0f,
        __builtin_amdgcn_rcpf(1.0f + __builtin_amdgcn_exp2f(N2LOG2E * x)), -1.0f);
}
// ds_swizzle BitMode: new_lane = (l & 0x1F) ^ XOR within each 32-lane half
template <int PAT>
__device__ __forceinline__ float swz(float v) {
    return __builtin_bit_cast(float,
        __builtin_amdgcn_ds_swizzle(__builtin_bit_cast(int, v), PAT));
}
#define XOR8  0x201F
#define XOR16 0x401F

// 2 chains per wave, 2 gate-rows per lane -> 2048 waves = 2 waves/SIMD.
// Lane l: chain cw=l>>5, w=l&31, unit u=w&15. Lane owns rows {w, w+32}:
//   w<16 : (i_u, g_u);  w>=16 : (f_u, o_u).
// After activations, one xor-16 ds_swizzle pair gives every lane all 4 gates.
// Cell update computed with w<16 semantics in all lanes (w>=16 lanes produce
// bounded garbage: |c'| <= |c|+1, no NaN; never stored). h written by w<16
// lanes only; broadcast-read back as 4x b128 (chains on disjoint bank halves).
// vs R6 (4 chains/wave, 1 wave/SIMD, VALUBusy 53%): per-wave issue halves,
// doubled occupancy hides the ~325cy/step dependency stall.
__global__ __launch_bounds__(256, 2) void lstm_ae_kernel(
    const float* __restrict__ x,
    const float* __restrict__ eWih, const float* __restrict__ eWhh,
    const float* __restrict__ ebih, const float* __restrict__ ebhh,
    const float* __restrict__ dWih, const float* __restrict__ dWhh,
    const float* __restrict__ dbih, const float* __restrict__ dbhh,
    const float* __restrict__ oW,   const float* __restrict__ ob,
    float* __restrict__ out)
{
    const int tid = threadIdx.x;
    const int wv  = tid >> 6;        // wave in block, 0..3
    const int l   = tid & 63;
    const int cw  = l >> 5;          // chain within wave, 0..1
    const int w   = l & 31;          // lane within chain
    const int u   = w & 15;          // hidden unit
    const bool loh = (w < 16);       // owns (i,g); else (f,o)
    const int r0  = w;               // row: i_u (w<16) or f_u (w>=16)
    const int r1  = w + 32;          // row: g_u (w<16) or o_u (w>=16)
    const int b   = blockIdx.x * 8 + wv * 2 + cw;

    __shared__ __align__(16) float hsh[4][2][16];      // chains 64B apart
    __shared__ __align__(16) float xsh[4][2][32][8];

    // act1: w<16 -> tanh (g), w>=16 -> sigmoid (o); log2e pre-folded
    const float ns1 = loh ? N2LOG2E : -LOG2E;
    const float m1  = loh ? 2.0f : 1.0f;
    const float c1  = loh ? -1.0f : 0.0f;
    const f32x2 zero2 = {0.0f, 0.0f};

    // ---------------- encoder weights ----------------
    f32x2 wh0[8], wh1[8], wi0[4], wi1[4];
    {
        const f32x2* p0 = (const f32x2*)(eWhh + r0 * 16);
        const f32x2* p1 = (const f32x2*)(eWhh + r1 * 16);
#pragma unroll
        for (int p = 0; p < 8; ++p) { wh0[p] = p0[p]; wh1[p] = p1[p]; }
        const f32x2* q0 = (const f32x2*)(eWih + r0 * 8);
        const f32x2* q1 = (const f32x2*)(eWih + r1 * 8);
#pragma unroll
        for (int p = 0; p < 4; ++p) { wi0[p] = q0[p]; wi1[p] = q1[p]; }
    }
    const float bias0 = ebih[r0] + ebhh[r0];
    const float bias1 = ebih[r1] + ebhh[r1];

    float c = 0.0f;
    f32x2 hb[8];
#pragma unroll
    for (int p = 0; p < 8; ++p) hb[p] = zero2;

    // x staging: lane covers steps (w>>1) and (w>>1)+16, half w&1 (16B each)
    const int sA = w >> 1, hA = (w & 1) * 4;
    const float* xbase = x + (size_t)b * (T_ * F_);
    f32x4v xrA = *(const f32x4v*)(xbase + sA * F_ + hA);
    f32x4v xrB = *(const f32x4v*)(xbase + (sA + 16) * F_ + hA);

    // ---------------- encoder ----------------
    for (int c0 = 0; c0 < T_; c0 += 32) {
        __builtin_amdgcn_wave_barrier();
        *(f32x4v*)&xsh[wv][cw][sA][hA]      = xrA;
        *(f32x4v*)&xsh[wv][cw][sA + 16][hA] = xrB;
        __builtin_amdgcn_wave_barrier();
        if (c0 + 32 < T_) {                  // prefetch next chunk; vmcnt
            xrA = *(const f32x4v*)(xbase + (c0 + 32 + sA) * F_ + hA);
            xrB = *(const f32x4v*)(xbase + (c0 + 48 + sA) * F_ + hA);
        }
        for (int s = 0; s < 32; ++s) {
            f32x4v xq0 = *(const f32x4v*)&xsh[wv][cw][s][0];
            f32x4v xq1 = *(const f32x4v*)&xsh[wv][cw][s][4];
            f32x2 x0 = SV2(xq0, 0, 1), x1 = SV2(xq0, 2, 3);
            f32x2 x2 = SV2(xq1, 0, 1), x3 = SV2(xq1, 2, 3);

            // two rows, two accumulator chains each (x-part first)
            f32x2 aa0 = pkfma(wi0[0], x0, f32x2{bias0, 0.0f});
            f32x2 ab0 = pkfma(wi0[1], x1, zero2);
            f32x2 aa1 = pkfma(wi1[0], x0, f32x2{bias1, 0.0f});
            f32x2 ab1 = pkfma(wi1[1], x1, zero2);
            aa0 = pkfma(wi0[2], x2, aa0); ab0 = pkfma(wi0[3], x3, ab0);
            aa1 = pkfma(wi1[2], x2, aa1); ab1 = pkfma(wi1[3], x3, ab1);
#pragma unroll
            for (int p = 0; p < 8; p += 2) {
                aa0 = pkfma(wh0[p],   hb[p],   aa0);
                ab0 = pkfma(wh0[p+1], hb[p+1], ab0);
                aa1 = pkfma(wh1[p],   hb[p],   aa1);
                ab1 = pkfma(wh1[p+1], hb[p+1], ab1);
            }
            f32x2 t0 = aa0 + ab0; const float s0 = t0.x + t0.y;
            f32x2 t1 = aa1 + ab1; const float s1 = t1.x + t1.y;

            const float a0 = sigf(s0);                      // i (or f)
            const float a1 = __builtin_fmaf(
                m1, __builtin_amdgcn_rcpf(1.0f + __builtin_amdgcn_exp2f(ns1 * s1)), c1);
            const float e0 = swz<XOR16>(a0);                // f (for w<16)
            const float e1 = swz<XOR16>(a1);                // o (for w<16)
            c = __builtin_fmaf(e0, c, a0 * a1);             // f*c + i*g
            const float ht = e1 * tanh_f(c);                // o*tanh(c)

            __builtin_amdgcn_wave_barrier();
            if (loh) hsh[wv][cw][u] = ht;
            __builtin_amdgcn_wave_barrier();
            const float* hp = &hsh[wv][cw][0];
            f32x4v h0 = *(const f32x4v*)&hp[0];
            f32x4v h1 = *(const f32x4v*)&hp[4];
            f32x4v h2 = *(const f32x4v*)&hp[8];
            f32x4v h3 = *(const f32x4v*)&hp[12];
            hb[0] = SV2(h0, 0, 1); hb[1] = SV2(h0, 2, 3);
            hb[2] = SV2(h1, 0, 1); hb[3] = SV2(h1, 2, 3);
            hb[4] = SV2(h2, 0, 1); hb[5] = SV2(h2, 2, 3);
            hb[6] = SV2(h3, 0, 1); hb[7] = SV2(h3, 2, 3);
        }
    }

    // ---------- decoder weights + constant input projection ----------
    f32x2 wd0[8], wd1[8];
    float xp0, xp1;
    {
        const f32x2* pi0 = (const f32x2*)(dWih + r0 * 16);
        const f32x2* pi1 = (const f32x2*)(dWih + r1 * 16);
        f32x2 a0 = zero2, a1 = zero2;
#pragma unroll
        for (int p = 0; p < 8; ++p) {
            a0 = pkfma(pi0[p], hb[p], a0);
            a1 = pkfma(pi1[p], hb[p], a1);
        }
        xp0 = dbih[r0] + dbhh[r0] + a0.x + a0.y;
        xp1 = dbih[r1] + dbhh[r1] + a1.x + a1.y;
        const f32x2* ph0 = (const f32x2*)(dWhh + r0 * 16);
        const f32x2* ph1 = (const f32x2*)(dWhh + r1 * 16);
#pragma unroll
        for (int p = 0; p < 8; ++p) { wd0[p] = ph0[p]; wd1[p] = ph1[p]; }
    }
    // out-proj: feature f=w&7, K-quarter kq=w>>3 (units 4kq..4kq+3)
    const int fo = w & 7, kq = w >> 3;
    f32x2 wo0 = ((const f32x2*)(oW + fo * 16))[kq * 2 + 0];
    f32x2 wo1 = ((const f32x2*)(oW + fo * 16))[kq * 2 + 1];
    const float obv = ob[fo];
    const bool st = (w < 8);
    float* outp = out + (size_t)b * (T_ * F_);

    c = 0.0f;
#pragma unroll
    for (int p = 0; p < 8; ++p) hb[p] = zero2;

    // ---------------- decoder + fused output projection ----------------
    for (int t = 0; t < T_; ++t) {
        f32x2 aa0 = pkfma(wd0[0], hb[0], f32x2{xp0, 0.0f});
        f32x2 ab0 = pkfma(wd0[1], hb[1], zero2);
        f32x2 aa1 = pkfma(wd1[0], hb[0], f32x2{xp1, 0.0f});
        f32x2 ab1 = pkfma(wd1[1], hb[1], zero2);
#pragma unroll
        for (int p = 2; p < 8; p += 2) {
            aa0 = pkfma(wd0[p],   hb[p],   aa0);
            ab0 = pkfma(wd0[p+1], hb[p+1], ab0);
            aa1 = pkfma(wd1[p],   hb[p],   aa1);
            ab1 = pkfma(wd1[p+1], hb[p+1], ab1);
        }
        f32x2 t0 = aa0 + ab0; const float s0 = t0.x + t0.y;
        f32x2 t1 = aa1 + ab1; const float s1 = t1.x + t1.y;

        const float a0 = sigf(s0);
        const float a1 = __builtin_fmaf(
            m1, __builtin_amdgcn_rcpf(1.0f + __builtin_amdgcn_exp2f(ns1 * s1)), c1);
        const float e0 = swz<XOR16>(a0);
        const float e1 = swz<XOR16>(a1);
        c = __builtin_fmaf(e0, c, a0 * a1);
        const float ht = e1 * tanh_f(c);

        __builtin_amdgcn_wave_barrier();
        if (loh) hsh[wv][cw][u] = ht;
        __builtin_amdgcn_wave_barrier();
        const float* hp = &hsh[wv][cw][0];
        f32x4v h0 = *(const f32x4v*)&hp[0];
        f32x4v h1 = *(const f32x4v*)&hp[4];
        f32x4v h2 = *(const f32x4v*)&hp[8];
        f32x4v h3 = *(const f32x4v*)&hp[12];
        hb[0] = SV2(h0, 0, 1); hb[1] = SV2(h0, 2, 3);
        hb[2] = SV2(h1, 0, 1); hb[3] = SV2(h1, 2, 3);
        hb[4] = SV2(h2, 0, 1); hb[5] = SV2(h2, 2, 3);
        hb[6] = SV2(h3, 0, 1); hb[7] = SV2(h3, 2, 3);

        // output projection: quarter-K partial + xor8/xor16 swizzle reduce
        f32x2 oa = pkfma(wo0, hb[kq * 2], zero2);
        oa = pkfma(wo1, hb[kq * 2 + 1], oa);
        float os = oa.x + oa.y;
        os += swz<XOR8>(os);
        os += swz<XOR16>(os);
        if (st) outp[t * F_ + w] = os + obv;
    }
}

extern "C" void kernel_launch(void* const* d_in, const int* in_sizes, int n_in,
                              void* d_out, int out_size, void* d_ws, size_t ws_size,
                              hipStream_t stream) {
    (void)in_sizes; (void)n_in; (void)d_ws; (void)ws_size; (void)out_size;
    lstm_ae_kernel<<<dim3(B_ / 8), dim3(256), 0, stream>>>(
        (const float*)d_in[0],
        (const float*)d_in[1], (const float*)d_in[2],
        (const float*)d_in[3], (const float*)d_in[4],
        (const float*)d_in[5], (const float*)d_in[6],
        (const float*)d_in[7], (const float*)d_in[8],
        (const float*)d_in[9], (const float*)d_in[10],
        (float*)d_out);
}

// Round 8
// 406.602 us; speedup vs baseline: 1.5112x; 1.5112x over previous
//
#include <hip/hip_runtime.h>

#define B_ 4096
#define T_ 512
#define F_ 8
#define H_ 16

typedef float f32x2 __attribute__((ext_vector_type(2)));
typedef float f32x4v __attribute__((ext_vector_type(4)));

__device__ __forceinline__ f32x2 pkfma(f32x2 a, f32x2 b, f32x2 c) {
    return __builtin_elementwise_fma(a, b, c);
}
#define SV2(v, a, b) __builtin_shufflevector(v, v, a, b)

#define LOG2E 1.442695041f
#define N2LOG2E (-2.885390082f)

__device__ __forceinline__ float sigf(float x) {
    return __builtin_amdgcn_rcpf(1.0f + __builtin_amdgcn_exp2f(-LOG2E * x));
}
__device__ __forceinline__ float tanh_f(float x) {
    return __builtin_fmaf(2.0f,
        __builtin_amdgcn_rcpf(1.0f + __builtin_amdgcn_exp2f(N2LOG2E * x)), -1.0f);
}

// DPP row_ror:K (full-rate VALU): dst[i] = src[(i-K)&15] within each 16-lane row
template <int K>
__device__ __forceinline__ float rotr(float v) {
    int i = __builtin_bit_cast(int, v);
    return __builtin_bit_cast(float,
        __builtin_amdgcn_update_dpp(i, i, 0x120 + K, 0xF, 0xF, false));
}
__device__ __forceinline__ void rot_all(float ht, float* hr) {
    hr[0]  = ht;
    hr[1]  = rotr<1>(ht);  hr[2]  = rotr<2>(ht);  hr[3]  = rotr<3>(ht);
    hr[4]  = rotr<4>(ht);  hr[5]  = rotr<5>(ht);  hr[6]  = rotr<6>(ht);
    hr[7]  = rotr<7>(ht);  hr[8]  = rotr<8>(ht);  hr[9]  = rotr<9>(ht);
    hr[10] = rotr<10>(ht); hr[11] = rotr<11>(ht); hr[12] = rotr<12>(ht);
    hr[13] = rotr<13>(ht); hr[14] = rotr<14>(ht); hr[15] = rotr<15>(ht);
}

// R6 layout (4 chains/wave, gate-quad locality) with the LDS h-broadcast
// replaced by DPP row-rotations. Lane l: chain cw=l>>4, unit u=l&15, owns all
// 4 gate rows {u,u+16,u+32,u+48} -> activations computed exactly once, no gate
// exchange. h share: hrot[k] = row_ror:k(ht) gives lane u the value h_{(u-k)&15}
// (15 independent full-rate DPP ops, ~4cy latency); weight columns are
// pre-rotated per lane at load time: wr[g][k] = W[row][(u-k)&15]. This removes
// all per-step LDS ops + barriers from the recurrent dependency chain (was
// ~150-200cy of ds latency per step = the 47% stall in R6's counters).
__global__ __launch_bounds__(256, 1) void lstm_ae_kernel(
    const float* __restrict__ x,
    const float* __restrict__ eWih, const float* __restrict__ eWhh,
    const float* __restrict__ ebih, const float* __restrict__ ebhh,
    const float* __restrict__ dWih, const float* __restrict__ dWhh,
    const float* __restrict__ dbih, const float* __restrict__ dbhh,
    const float* __restrict__ oW,   const float* __restrict__ ob,
    float* __restrict__ out)
{
    const int tid = threadIdx.x;
    const int wv  = tid >> 6;        // wave in block
    const int l   = tid & 63;
    const int cw  = l >> 4;          // chain within wave, 0..3
    const int u   = l & 15;          // hidden unit (lane within 16-row)
    const int bw  = blockIdx.x * 16 + wv * 4;
    const int b   = bw + cw;

    __shared__ __align__(16) f32x2 xsh[4][4][33][4];   // x staging (R6 layout)

    const f32x2 zero2 = {0.0f, 0.0f};

    // ---------------- encoder weights (rotated gather) ----------------
    float wr[4][16];                 // wr[g][k] = eWhh[g*16+u][(u-k)&15]
    f32x2 wi[4][4];
    float bias[4];
#pragma unroll
    for (int g = 0; g < 4; ++g) {
        const int r = g * 16 + u;
#pragma unroll
        for (int k = 0; k < 16; ++k)
            wr[g][k] = eWhh[r * 16 + ((u - k) & 15)];
        const f32x2* pih = (const f32x2*)(eWih + r * 8);
#pragma unroll
        for (int p = 0; p < 4; ++p) wi[g][p] = pih[p];
        bias[g] = ebih[r] + ebhh[r];
    }

    float c = 0.0f;
    float hrot[16];
#pragma unroll
    for (int k = 0; k < 16; ++k) hrot[k] = 0.0f;

    // x chunk prefetch: iter i covers chain bw+i, step c0+(l>>1), half l&1
    const int ps = l >> 1, phx = l & 1;
    f32x4v xr[4];
#pragma unroll
    for (int i = 0; i < 4; ++i)
        xr[i] = *(const f32x4v*)(x + ((size_t)(bw + i) * T_ + ps) * F_ + phx * 4);

    // ---------------- encoder ----------------
    for (int c0 = 0; c0 < T_; c0 += 32) {
        __builtin_amdgcn_wave_barrier();
#pragma unroll
        for (int i = 0; i < 4; ++i)
            *(f32x4v*)&xsh[wv][i][ps][phx * 2] = xr[i];
        __builtin_amdgcn_wave_barrier();
        if (c0 + 32 < T_) {
#pragma unroll
            for (int i = 0; i < 4; ++i)
                xr[i] = *(const f32x4v*)(
                    x + ((size_t)(bw + i) * T_ + (c0 + 32 + ps)) * F_ + phx * 4);
        }
        for (int s = 0; s < 32; ++s) {
            f32x4v xq0 = *(const f32x4v*)&xsh[wv][cw][s][0];
            f32x4v xq1 = *(const f32x4v*)&xsh[wv][cw][s][2];
            f32x2 x0 = SV2(xq0, 0, 1), x1 = SV2(xq0, 2, 3);
            f32x2 x2 = SV2(xq1, 0, 1), x3 = SV2(xq1, 2, 3);

            float sg[4];
#pragma unroll
            for (int g = 0; g < 4; ++g) {
                // x-part (h-independent, schedules early)
                f32x2 pa = pkfma(wi[g][0], x0, f32x2{bias[g], 0.0f});
                f32x2 pb = pkfma(wi[g][1], x1, zero2);
                pa = pkfma(wi[g][2], x2, pa);
                pb = pkfma(wi[g][3], x3, pb);
                f32x2 ts = pa + pb;
                float cA = ts.x + ts.y, cB = 0.0f;
#pragma unroll
                for (int k = 0; k < 16; k += 2) {
                    cA = __builtin_fmaf(wr[g][k],     hrot[k],     cA);
                    cB = __builtin_fmaf(wr[g][k + 1], hrot[k + 1], cB);
                }
                sg[g] = cA + cB;
            }
            const float gi = sigf(sg[0]);
            const float gf = sigf(sg[1]);
            const float gg = tanh_f(sg[2]);
            const float go = sigf(sg[3]);
            c = __builtin_fmaf(gf, c, gi * gg);
            const float ht = go * tanh_f(c);
            rot_all(ht, hrot);
        }
    }

    // ---------- decoder weights (rotated) + constant input projection ------
    float wd[4][16], wo[16], xp[4];
#pragma unroll
    for (int g = 0; g < 4; ++g) {
        const int r = g * 16 + u;
        float a = 0.0f;
#pragma unroll
        for (int k = 0; k < 16; ++k) {
            wd[g][k] = dWhh[r * 16 + ((u - k) & 15)];
            a = __builtin_fmaf(dWih[r * 16 + ((u - k) & 15)], hrot[k], a);
        }
        xp[g] = dbih[r] + dbhh[r] + a;
    }
#pragma unroll
    for (int k = 0; k < 16; ++k)
        wo[k] = oW[(u & 7) * 16 + ((u - k) & 15)];
    const float obv = ob[u & 7];
    const bool st = (u < 8);
    float* outp = out + (size_t)b * (T_ * F_);

    c = 0.0f;
#pragma unroll
    for (int k = 0; k < 16; ++k) hrot[k] = 0.0f;

    // ---------------- decoder + fused output projection ----------------
    for (int t = 0; t < T_; ++t) {
        float sg[4];
#pragma unroll
        for (int g = 0; g < 4; ++g) {
            float cA = xp[g], cB = 0.0f;
#pragma unroll
            for (int k = 0; k < 16; k += 2) {
                cA = __builtin_fmaf(wd[g][k],     hrot[k],     cA);
                cB = __builtin_fmaf(wd[g][k + 1], hrot[k + 1], cB);
            }
            sg[g] = cA + cB;
        }
        const float gi = sigf(sg[0]);
        const float gf = sigf(sg[1]);
        const float gg = tanh_f(sg[2]);
        const float go = sigf(sg[3]);
        c = __builtin_fmaf(gf, c, gi * gg);
        const float ht = go * tanh_f(c);
        rot_all(ht, hrot);

        // fused output projection from the just-updated h (feature u&7)
        float oA = obv, oB = 0.0f;
#pragma unroll
        for (int k = 0; k < 16; k += 2) {
            oA = __builtin_fmaf(wo[k],     hrot[k],     oA);
            oB = __builtin_fmaf(wo[k + 1], hrot[k + 1], oB);
        }
        if (st) outp[t * F_ + u] = oA + oB;
    }
}

extern "C" void kernel_launch(void* const* d_in, const int* in_sizes, int n_in,
                              void* d_out, int out_size, void* d_ws, size_t ws_size,
                              hipStream_t stream) {
    (void)in_sizes; (void)n_in; (void)d_ws; (void)ws_size; (void)out_size;
    lstm_ae_kernel<<<dim3(B_ / 16), dim3(256), 0, stream>>>(
        (const float*)d_in[0],
        (const float*)d_in[1], (const float*)d_in[2],
        (const float*)d_in[3], (const float*)d_in[4],
        (const float*)d_in[5], (const float*)d_in[6],
        (const float*)d_in[7], (const float*)d_in[8],
        (const float*)d_in[9], (const float*)d_in[10],
        (float*)d_out);
}

// Round 9
// 387.160 us; speedup vs baseline: 1.5871x; 1.0502x over previous
//
#include <hip/hip_runtime.h>

#define B_ 4096
#define T_ 512
#define F_ 8
#define H_ 16

typedef float f32x2 __attribute__((ext_vector_type(2)));
typedef float f32x4v __attribute__((ext_vector_type(4)));

__device__ __forceinline__ f32x2 pkfma(f32x2 a, f32x2 b, f32x2 c) {
    return __builtin_elementwise_fma(a, b, c);
}
#define SV2(v, a, b) __builtin_shufflevector(v, v, a, b)

#define LOG2E 1.442695041f
#define N2LOG2E (-2.885390082f)

__device__ __forceinline__ float sigf(float x) {
    return __builtin_amdgcn_rcpf(1.0f + __builtin_amdgcn_exp2f(-LOG2E * x));
}
__device__ __forceinline__ float tanh_f(float x) {
    return __builtin_fmaf(2.0f,
        __builtin_amdgcn_rcpf(1.0f + __builtin_amdgcn_exp2f(N2LOG2E * x)), -1.0f);
}

// DPP row_ror:K (full-rate VALU): dst[i] = src[(i-K)&15] within each 16-lane row
template <int K>
__device__ __forceinline__ float rotr(float v) {
    int i = __builtin_bit_cast(int, v);
    return __builtin_bit_cast(float,
        __builtin_amdgcn_update_dpp(i, i, 0x120 + K, 0xF, 0xF, false));
}

// R6 layout (4 chains/wave, gate-quad locality: lane l = chain l>>4, unit
// u=l&15, owns gate rows {u,u+16,u+32,u+48}) with the h-broadcast done by DPP
// row-rotations IN PK PAIRS:
//   hp[j] = (rotr<2j>(ht), rotr<2j+1>(ht)) = (h_{(u-2j)&15}, h_{(u-2j-1)&15})
//   wr2[g][j] = (W[r][(u-2j)&15], W[r][(u-2j-1)&15])
//   sum_j pk(wr2[g][j], hp[j]) covers all 16 units.
// vs R6: removes all per-step LDS + barriers from the recurrent chain (the
// 47% stall). vs R8: keeps v_pk_fma_f32 issue rates (R8's scalar matvec cost
// +150cy/step). Rotation semantics HW-validated by R8 (passed, same absmax).
// x staging stays in LDS with a step-level register pipeline (read s+1 during
// compute of s) so ds_read latency is off the serial path.
__global__ __launch_bounds__(256, 1) void lstm_ae_kernel(
    const float* __restrict__ x,
    const float* __restrict__ eWih, const float* __restrict__ eWhh,
    const float* __restrict__ ebih, const float* __restrict__ ebhh,
    const float* __restrict__ dWih, const float* __restrict__ dWhh,
    const float* __restrict__ dbih, const float* __restrict__ dbhh,
    const float* __restrict__ oW,   const float* __restrict__ ob,
    float* __restrict__ out)
{
    const int tid = threadIdx.x;
    const int wv  = tid >> 6;        // wave in block
    const int l   = tid & 63;
    const int cw  = l >> 4;          // chain within wave, 0..3
    const int u   = l & 15;          // hidden unit (lane within 16-row)
    const int bw  = blockIdx.x * 16 + wv * 4;
    const int b   = bw + cw;

    __shared__ __align__(16) f32x2 xsh[4][4][33][4];   // x staging only

    const f32x2 zero2 = {0.0f, 0.0f};

    // ---------------- encoder weights (rotated pk pairs) ----------------
    f32x2 wr2[4][8], wi[4][4];
    float bias[4];
#pragma unroll
    for (int g = 0; g < 4; ++g) {
        const int r = g * 16 + u;
#pragma unroll
        for (int j = 0; j < 8; ++j)
            wr2[g][j] = f32x2{eWhh[r * 16 + ((u - 2 * j) & 15)],
                              eWhh[r * 16 + ((u - 2 * j - 1) & 15)]};
        const f32x2* pih = (const f32x2*)(eWih + r * 8);
#pragma unroll
        for (int p = 0; p < 4; ++p) wi[g][p] = pih[p];
        bias[g] = ebih[r] + ebhh[r];
    }

    float c = 0.0f;
    f32x2 hp[8];
#pragma unroll
    for (int j = 0; j < 8; ++j) hp[j] = zero2;

    // x chunk prefetch: iter i covers chain bw+i, step c0+(l>>1), half l&1
    const int ps = l >> 1, phx = l & 1;
    f32x4v xr[4];
#pragma unroll
    for (int i = 0; i < 4; ++i)
        xr[i] = *(const f32x4v*)(x + ((size_t)(bw + i) * T_ + ps) * F_ + phx * 4);

    // ---------------- encoder ----------------
    for (int c0 = 0; c0 < T_; c0 += 32) {
        __builtin_amdgcn_wave_barrier();
#pragma unroll
        for (int i = 0; i < 4; ++i)
            *(f32x4v*)&xsh[wv][i][ps][phx * 2] = xr[i];
        __builtin_amdgcn_wave_barrier();
        if (c0 + 32 < T_) {
#pragma unroll
            for (int i = 0; i < 4; ++i)
                xr[i] = *(const f32x4v*)(
                    x + ((size_t)(bw + i) * T_ + (c0 + 32 + ps)) * F_ + phx * 4);
        }
        // step-level x pipeline: LDS reads for s+1 issued during compute of s
        f32x4v xq0 = *(const f32x4v*)&xsh[wv][cw][0][0];
        f32x4v xq1 = *(const f32x4v*)&xsh[wv][cw][0][2];
        for (int s = 0; s < 32; ++s) {
            // s=31 reads pad row 32 (in-bounds, discarded)
            f32x4v nq0 = *(const f32x4v*)&xsh[wv][cw][s + 1][0];
            f32x4v nq1 = *(const f32x4v*)&xsh[wv][cw][s + 1][2];
            f32x2 x0 = SV2(xq0, 0, 1), x1 = SV2(xq0, 2, 3);
            f32x2 x2 = SV2(xq1, 0, 1), x3 = SV2(xq1, 2, 3);

            float sg[4];
#pragma unroll
            for (int g = 0; g < 4; ++g) {
                f32x2 aa = pkfma(wi[g][0], x0, f32x2{bias[g], 0.0f});
                f32x2 ab = pkfma(wi[g][1], x1, zero2);
                aa = pkfma(wi[g][2], x2, aa);
                ab = pkfma(wi[g][3], x3, ab);
#pragma unroll
                for (int j = 0; j < 8; j += 2) {
                    aa = pkfma(wr2[g][j],     hp[j],     aa);
                    ab = pkfma(wr2[g][j + 1], hp[j + 1], ab);
                }
                f32x2 ts = aa + ab;
                sg[g] = ts.x + ts.y;
            }
            const float gi = sigf(sg[0]);
            const float gf = sigf(sg[1]);
            const float gg = tanh_f(sg[2]);
            const float go = sigf(sg[3]);
            c = __builtin_fmaf(gf, c, gi * gg);
            const float ht = go * tanh_f(c);

            hp[0] = f32x2{ht,            rotr<1>(ht)};
            hp[1] = f32x2{rotr<2>(ht),   rotr<3>(ht)};
            hp[2] = f32x2{rotr<4>(ht),   rotr<5>(ht)};
            hp[3] = f32x2{rotr<6>(ht),   rotr<7>(ht)};
            hp[4] = f32x2{rotr<8>(ht),   rotr<9>(ht)};
            hp[5] = f32x2{rotr<10>(ht),  rotr<11>(ht)};
            hp[6] = f32x2{rotr<12>(ht),  rotr<13>(ht)};
            hp[7] = f32x2{rotr<14>(ht),  rotr<15>(ht)};
            xq0 = nq0; xq1 = nq1;
        }
    }

    // ---------- decoder weights (rotated pairs) + constant x-projection -----
    f32x2 wd2[4][8], wo2[8];
    float xp[4];
#pragma unroll
    for (int g = 0; g < 4; ++g) {
        const int r = g * 16 + u;
        f32x2 a = zero2;
#pragma unroll
        for (int j = 0; j < 8; ++j) {
            f32x2 wij = f32x2{dWih[r * 16 + ((u - 2 * j) & 15)],
                              dWih[r * 16 + ((u - 2 * j - 1) & 15)]};
            a = pkfma(wij, hp[j], a);
            wd2[g][j] = f32x2{dWhh[r * 16 + ((u - 2 * j) & 15)],
                              dWhh[r * 16 + ((u - 2 * j - 1) & 15)]};
        }
        xp[g] = dbih[r] + dbhh[r] + a.x + a.y;
    }
    const int fo = u & 7;
#pragma unroll
    for (int j = 0; j < 8; ++j)
        wo2[j] = f32x2{oW[fo * 16 + ((u - 2 * j) & 15)],
                       oW[fo * 16 + ((u - 2 * j - 1) & 15)]};
    const float obv = ob[fo];
    const bool st = (u < 8);
    float* outp = out + (size_t)b * (T_ * F_);

    c = 0.0f;
#pragma unroll
    for (int j = 0; j < 8; ++j) hp[j] = zero2;

    // ---------------- decoder + fused output projection ----------------
#pragma unroll 2
    for (int t = 0; t < T_; ++t) {
        float sg[4];
#pragma unroll
        for (int g = 0; g < 4; ++g) {
            f32x2 aa = pkfma(wd2[g][0], hp[0], f32x2{xp[g], 0.0f});
            f32x2 ab = pkfma(wd2[g][1], hp[1], zero2);
#pragma unroll
            for (int j = 2; j < 8; j += 2) {
                aa = pkfma(wd2[g][j],     hp[j],     aa);
                ab = pkfma(wd2[g][j + 1], hp[j + 1], ab);
            }
            f32x2 ts = aa + ab;
            sg[g] = ts.x + ts.y;
        }
        const float gi = sigf(sg[0]);
        const float gf = sigf(sg[1]);
        const float gg = tanh_f(sg[2]);
        const float go = sigf(sg[3]);
        c = __builtin_fmaf(gf, c, gi * gg);
        const float ht = go * tanh_f(c);

        hp[0] = f32x2{ht,            rotr<1>(ht)};
        hp[1] = f32x2{rotr<2>(ht),   rotr<3>(ht)};
        hp[2] = f32x2{rotr<4>(ht),   rotr<5>(ht)};
        hp[3] = f32x2{rotr<6>(ht),   rotr<7>(ht)};
        hp[4] = f32x2{rotr<8>(ht),   rotr<9>(ht)};
        hp[5] = f32x2{rotr<10>(ht),  rotr<11>(ht)};
        hp[6] = f32x2{rotr<12>(ht),  rotr<13>(ht)};
        hp[7] = f32x2{rotr<14>(ht),  rotr<15>(ht)};

        // fused output projection (feature u&7), off the recurrent path
        f32x2 oa = pkfma(wo2[0], hp[0], f32x2{obv, 0.0f});
        f32x2 obb = pkfma(wo2[1], hp[1], zero2);
#pragma unroll
        for (int j = 2; j < 8; j += 2) {
            oa  = pkfma(wo2[j],     hp[j],     oa);
            obb = pkfma(wo2[j + 1], hp[j + 1], obb);
        }
        f32x2 to = oa + obb;
        if (st) outp[t * F_ + u] = to.x + to.y;
    }
}

extern "C" void kernel_launch(void* const* d_in, const int* in_sizes, int n_in,
                              void* d_out, int out_size, void* d_ws, size_t ws_size,
                              hipStream_t stream) {
    (void)in_sizes; (void)n_in; (void)d_ws; (void)ws_size; (void)out_size;
    lstm_ae_kernel<<<dim3(B_ / 16), dim3(256), 0, stream>>>(
        (const float*)d_in[0],
        (const float*)d_in[1], (const float*)d_in[2],
        (const float*)d_in[3], (const float*)d_in[4],
        (const float*)d_in[5], (const float*)d_in[6],
        (const float*)d_in[7], (const float*)d_in[8],
        (const float*)d_in[9], (const float*)d_in[10],
        (float*)d_out);
}